// Round 3
// baseline (61.463 us; speedup 1.0000x reference)
//
#include <hip/hip_runtime.h>
#include <math.h>

// Until_15753940041804: soft "until" operator.
// best[b,t,c] = log( sum_{k=0..63} 1/(S_k + exp(-s*psi[b,t+k,c])) ) / s
//   S_0 = exp(-s*1.0),  S_k = sum_{j<k} exp(-s*phi[b,t+j,c])  (k>=1).
// Padding past T: ep=0 (phi pad +1e4), eq=+inf (psi pad -1e4) reproduces the
// reference's pad AND its 'valid' mask exactly (rcp(inf)=0), so the k-loop is
// a constant 64 trips.
//
// R3 change vs R2: kernel was LDS-issue bound (8 waves x 64 ds_read_b128
// x ~12cyc = 6144 cyc/CU vs ~1.5us VALU). Now each thread computes TWO
// adjacent outputs (t=2*tid, 2*tid+1) so one ds_read_b128 of element t+j
// feeds both (k=j and k=j-1) -> LDS instr/output halved. Storage is
// deinterleaved into even/odd arrays so reads stay 16B-stride
// (conflict-free); naive 32B stride would be a 4-way conflict (1.58x).
// Tile=512 outputs, 256 threads, grid (4,64)=256 blocks = 1 block/CU.

#define T_DIM    2048
#define W_WIN    64
#define TILE     512
#define NTHREADS 256
#define STAGE    (TILE + W_WIN)   // 576 staged elements
#define HALF     (STAGE / 2)      // 288 per parity array

__global__ __launch_bounds__(NTHREADS) void until_kernel(
    const float* __restrict__ phi,
    const float* __restrict__ psi,
    const int*  __restrict__ scale_p,
    float* __restrict__ out)
{
    // float4: x = ep ch0, y = ep ch1, z = eq ch0, w = eq ch1
    __shared__ float4 s_e[HALF];   // even tile-relative indices
    __shared__ float4 s_o[HALF];   // odd  tile-relative indices

    const int b   = blockIdx.y;
    const int t0  = blockIdx.x * TILE;
    const int tid = threadIdx.x;
    const float s  = (float)(*scale_p);
    const float ns = -s;

    const float2* __restrict__ phi2 = (const float2*)(phi + (size_t)b * T_DIM * 2);
    const float2* __restrict__ psi2 = (const float2*)(psi + (size_t)b * T_DIM * 2);

    // Stage: exp once per element, deinterleaved by parity.
    for (int i = tid; i < STAGE; i += NTHREADS) {
        int t = t0 + i;
        float4 v;
        if (t < T_DIM) {
            float2 pv = phi2[t];
            float2 qv = psi2[t];
            v.x = __expf(ns * pv.x);
            v.y = __expf(ns * pv.y);
            v.z = __expf(ns * qv.x);
            v.w = __expf(ns * qv.y);
        } else {
            v.x = 0.f; v.y = 0.f;
            v.z = INFINITY; v.w = INFINITY;
        }
        if (i & 1) s_o[i >> 1] = v;
        else       s_e[i >> 1] = v;
    }
    __syncthreads();

    const float Es = __expf(ns);   // k==0 term: min_phi forced to 1.0

    // Outputs ta = t0+2*tid (even), tb = ta+1 (odd).
    // Element m = 2*tid + j serves ta at k=j (j<=63) and tb at k=j-1 (j>=1).

    // j = 0: element E[tid]
    float4 va = s_e[tid];
    float accA0 = __builtin_amdgcn_rcpf(Es + va.z);
    float accA1 = __builtin_amdgcn_rcpf(Es + va.w);
    float sumA0 = va.x, sumA1 = va.y;

    // j = 1: element O[tid]
    float4 vb = s_o[tid];
    float accB0 = __builtin_amdgcn_rcpf(Es + vb.z);
    float accB1 = __builtin_amdgcn_rcpf(Es + vb.w);
    accA0 += __builtin_amdgcn_rcpf(sumA0 + vb.z);
    accA1 += __builtin_amdgcn_rcpf(sumA1 + vb.w);
    sumA0 += vb.x; sumA1 += vb.y;
    float sumB0 = vb.x, sumB1 = vb.y;

    // j = 2..63
    #pragma unroll
    for (int h = 1; h <= 31; ++h) {
        float4 v = s_e[tid + h];          // j = 2h   (ta k=2h, tb k=2h-1)
        accA0 += __builtin_amdgcn_rcpf(sumA0 + v.z);
        accA1 += __builtin_amdgcn_rcpf(sumA1 + v.w);
        accB0 += __builtin_amdgcn_rcpf(sumB0 + v.z);
        accB1 += __builtin_amdgcn_rcpf(sumB1 + v.w);
        sumA0 += v.x; sumA1 += v.y;
        sumB0 += v.x; sumB1 += v.y;

        float4 u = s_o[tid + h];          // j = 2h+1 (ta k=2h+1, tb k=2h)
        accA0 += __builtin_amdgcn_rcpf(sumA0 + u.z);
        accA1 += __builtin_amdgcn_rcpf(sumA1 + u.w);
        accB0 += __builtin_amdgcn_rcpf(sumB0 + u.z);
        accB1 += __builtin_amdgcn_rcpf(sumB1 + u.w);
        sumA0 += u.x; sumA1 += u.y;
        sumB0 += u.x; sumB1 += u.y;
    }

    // j = 64: element E[tid+32] — only tb at k=63
    float4 vz = s_e[tid + 32];
    accB0 += __builtin_amdgcn_rcpf(sumB0 + vz.z);
    accB1 += __builtin_amdgcn_rcpf(sumB1 + vz.w);

    // Store both outputs (2 t's x 2 ch) as one coalesced float4.
    const float inv_s = 1.0f / s;
    float4 o;
    o.x = __logf(accA0) * inv_s;
    o.y = __logf(accA1) * inv_s;
    o.z = __logf(accB0) * inv_s;
    o.w = __logf(accB1) * inv_s;
    float4* __restrict__ out4 = (float4*)(out + (size_t)b * T_DIM * 2);
    out4[(t0 >> 1) + tid] = o;
}

extern "C" void kernel_launch(void* const* d_in, const int* in_sizes, int n_in,
                              void* d_out, int out_size, void* d_ws, size_t ws_size,
                              hipStream_t stream) {
    const float* phi   = (const float*)d_in[0];
    const float* psi   = (const float*)d_in[1];
    const int*   scale = (const int*)d_in[2];
    float* out = (float*)d_out;

    const int B = in_sizes[0] / (T_DIM * 2);   // 64
    dim3 grid(T_DIM / TILE, B);                // (4, 64) = 256 blocks = 1/CU
    until_kernel<<<grid, dim3(NTHREADS), 0, stream>>>(phi, psi, scale, out);
}